// Round 1
// baseline (354.569 us; speedup 1.0000x reference)
//
#include <hip/hip_runtime.h>

#define NSTEPS 24
#define HALFW  2048
#define ROWS   4

// Round-1 swizzle — MEASURED 0 bank conflicts at b32 scalar.
#define SWZ(q) ((q) ^ (((q) >> 4) & 31))
#define QA(e) (((e) << 8) | t)                              // bits 11..8 in regs
#define QB(e) ((((t) >> 4) << 8) | ((e) << 4) | ((t) & 15)) // bits 7..4  in regs
#define QC(e) (((t) << 4) | (e))                            // bits 3..0  in regs

#define SB() __builtin_amdgcn_sched_barrier(0)

// tab[(d*2048 + t*8 + p)*2] = {cos,sin} in the main kernel's access order.
__global__ void build_tab_kernel(const float* __restrict__ params,
                                 float* __restrict__ tab) {
    int idx = blockIdx.x * 256 + threadIdx.x;
    if (idx >= NSTEPS * HALFW) return;
    int d  = idx >> 11;
    int j  = idx & (HALFW - 1);
    int t  = j >> 3;
    int p  = j & 7;
    int dd = d % 12;
    int grp = dd >> 2;            // 0: bits 11..8, 1: bits 7..4, 2: bits 3..0
    int k  = 3 - (dd & 3);        // butterfly bit within the nibble
    int e0 = ((p >> k) << (k + 1)) | (p & ((1 << k) - 1)); // insert 0 at bit k
    int q0;
    if (grp == 0)      q0 = (e0 << 8) | t;
    else if (grp == 1) q0 = ((t >> 4) << 8) | (e0 << 4) | (t & 15);
    else               q0 = (t << 4) | e0;
    int l = ((q0 << dd) | (q0 >> (12 - dd))) & 0xFFF;       // rotl12(q0, dd)
    l &= 0x7FF;
    float theta = params[l * NSTEPS + d];   // params (2048, 24) row-major
    float s, c;
    sincosf(theta, &s, &c);
    tab[2 * idx]     = c;
    tab[2 * idx + 1] = s;
}

// SROA-safe 16-float load (4x dwordx4, scalar unpack, no local punning).
__device__ __forceinline__ void ldcs(float (&dst)[16], const float* __restrict__ p) {
    const float4* ap = (const float4*)p;
    float4 q0 = ap[0], q1 = ap[1], q2 = ap[2], q3 = ap[3];
    dst[0]  = q0.x; dst[1]  = q0.y; dst[2]  = q0.z; dst[3]  = q0.w;
    dst[4]  = q1.x; dst[5]  = q1.y; dst[6]  = q1.z; dst[7]  = q1.w;
    dst[8]  = q2.x; dst[9]  = q2.y; dst[10] = q2.z; dst[11] = q2.w;
    dst[12] = q3.x; dst[13] = q3.y; dst[14] = q3.z; dst[15] = q3.w;
}

// One butterfly step (bit KK) on rows [R0, R0+NR).
template<int KK, int R0, int NR>
__device__ __forceinline__ void butterfly_rows(float (&r)[ROWS][16],
                                               const float (&cs)[16]) {
    #pragma unroll
    for (int p = 0; p < 8; ++p) {
        const int e0 = ((p >> KK) << (KK + 1)) | (p & ((1 << KK) - 1));
        const int e1 = e0 | (1 << KK);
        const float c = cs[2 * p], s = cs[2 * p + 1];
        #pragma unroll
        for (int rr = R0; rr < R0 + NR; ++rr) {
            const float v0 = r[rr][e0], v1 = r[rr][e1];
            r[rr][e0] = fmaf(c, v0, s * v1);
            r[rr][e1] = fmaf(c, v1, -s * v0);
        }
    }
}

// 4 butterfly steps on rows [R0, R0+NR). If PF, reload each cs buffer with
// the NEXT group's corresponding step right after its last use (this must
// only be enabled on the FINAL row-pass of a group).
template<int BASE, int R0, int NR, bool PF>
__device__ __forceinline__ void group4_rows(float (&r)[ROWS][16],
        float (&c0)[16], float (&c1)[16], float (&c2)[16], float (&c3)[16],
        const float* __restrict__ tb) {
    butterfly_rows<3, R0, NR>(r, c0);
    if constexpr (PF) { ldcs(c0, tb + (BASE + 4) * 4096); SB(); }
    butterfly_rows<2, R0, NR>(r, c1);
    if constexpr (PF) { ldcs(c1, tb + (BASE + 5) * 4096); SB(); }
    butterfly_rows<1, R0, NR>(r, c2);
    if constexpr (PF) { ldcs(c2, tb + (BASE + 6) * 4096); SB(); }
    butterfly_rows<0, R0, NR>(r, c3);
    if constexpr (PF) { ldcs(c3, tb + (BASE + 7) * 4096); SB(); }
}

// Fused transition + next group, 32 KiB LDS (2 row-buffers), 4 barriers:
//   store r0/r1 ; sync ; load r0/r1 ; sync ;
//   store r2/r3 ; [compute group on rows 0/1 — covers the stores] ; sync ;
//   load  r2/r3 ; [compute group on rows 2/3 + cs prefetch] ; [tail sync]
// Rows are fully independent, so computing rows 0/1 before rows 2/3 have
// been transposed is legal. Swizzled b32 pattern per buffer is identical to
// the measured-conflict-free TRANS.
#define TG(BASE, QS, QD, PFN, TAILSYNC) do {                                  \
    _Pragma("unroll")                                                         \
    for (int e = 0; e < 16; ++e) {                                            \
        const int a = SWZ(QS(e));                                             \
        lds0[a] = r[0][e];                                                    \
        lds1[a] = r[1][e];                                                    \
    }                                                                         \
    __syncthreads();                                                          \
    _Pragma("unroll")                                                         \
    for (int e = 0; e < 16; ++e) {                                            \
        const int a = SWZ(QD(e));                                             \
        r[0][e] = lds0[a];                                                    \
        r[1][e] = lds1[a];                                                    \
    }                                                                         \
    __syncthreads();                                                          \
    _Pragma("unroll")                                                         \
    for (int e = 0; e < 16; ++e) {                                            \
        const int a = SWZ(QS(e));                                             \
        lds0[a] = r[2][e];                                                    \
        lds1[a] = r[3][e];                                                    \
    }                                                                         \
    group4_rows<BASE, 0, 2, false>(r, c0, c1, c2, c3, tb);                    \
    __syncthreads();                                                          \
    _Pragma("unroll")                                                         \
    for (int e = 0; e < 16; ++e) {                                            \
        const int a = SWZ(QD(e));                                             \
        r[2][e] = lds0[a];                                                    \
        r[3][e] = lds1[a];                                                    \
    }                                                                         \
    group4_rows<BASE, 2, 2, PFN>(r, c0, c1, c2, c3, tb);                      \
    if (TAILSYNC) __syncthreads();                                            \
} while (0)

__global__ __launch_bounds__(256, 4)   // 4 waves/SIMD: cap 128 VGPR (was 100)
void bfly_kernel(const float* __restrict__ X,
                 const float* __restrict__ tab,
                 float* __restrict__ Y) {
    __shared__ float lds0[4096];       // 2 x 16 KiB = 32 KiB -> 4 blocks/CU
    __shared__ float lds1[4096];
    const int t = threadIdx.x;
    const size_t row0 = (size_t)blockIdx.x * ROWS;

    const float* tb = tab + t * 16;
    float c0[16], c1[16], c2[16], c3[16];
    ldcs(c0, tb + 0 * 4096);
    ldcs(c1, tb + 1 * 4096);
    ldcs(c2, tb + 2 * 4096);
    ldcs(c3, tb + 3 * 4096);
    SB();

    float r[ROWS][16];
    #pragma unroll
    for (int rr = 0; rr < ROWS; ++rr) {
        const float* xr = X + (row0 + rr) * 4096;
        #pragma unroll
        for (int e = 0; e < 16; ++e)
            r[rr][e] = xr[QA(e)];  // coalesced: consecutive lanes, consecutive addr
    }

    group4_rows<0, 0, 4, true>(r, c0, c1, c2, c3, tb);  // steps 0..3 (bits 11..8)
    TG(4,  QA, QB, true,  true);                        // steps 4..7   (bits 7..4)
    TG(8,  QB, QC, true,  true);                        // steps 8..11  (bits 3..0)
    TG(12, QC, QA, true,  true);                        // steps 12..15 (bits 11..8)
    TG(16, QA, QB, true,  true);                        // steps 16..19 (bits 7..4)
    TG(20, QB, QC, false, false);                       // steps 20..23 (bits 3..0)

    // grouping C: thread t holds 16 consecutive outputs -> 4x float4 stores
    #pragma unroll
    for (int rr = 0; rr < ROWS; ++rr) {
        float* yr = Y + (row0 + rr) * 4096;
        #pragma unroll
        for (int v = 0; v < 4; ++v) {
            float4 o;
            o.x = r[rr][4 * v + 0];
            o.y = r[rr][4 * v + 1];
            o.z = r[rr][4 * v + 2];
            o.w = r[rr][4 * v + 3];
            *(float4*)&yr[t * 16 + 4 * v] = o;
        }
    }
}

extern "C" void kernel_launch(void* const* d_in, const int* in_sizes, int n_in,
                              void* d_out, int out_size, void* d_ws, size_t ws_size,
                              hipStream_t stream) {
    const float* X      = (const float*)d_in[0];
    const float* params = (const float*)d_in[1];
    float* out = (float*)d_out;
    float* tab = (float*)d_ws;   // 24*2048*2*4 = 393,216 bytes

    hipLaunchKernelGGL(build_tab_kernel,
                       dim3((NSTEPS * HALFW + 255) / 256), dim3(256), 0, stream,
                       params, tab);
    hipLaunchKernelGGL(bfly_kernel,
                       dim3(8192 / ROWS), dim3(256), 0, stream,
                       X, tab, out);
}

// Round 2
// 108.133 us; speedup vs baseline: 3.2790x; 3.2790x over previous
//
#include <hip/hip_runtime.h>

#define NSTEPS 24
#define HALFW  2048
#define ROWS   4

// Round-1 swizzle — MEASURED 0 bank conflicts at b32 scalar.
#define SWZ(q) ((q) ^ (((q) >> 4) & 31))
#define QA(e) (((e) << 8) | t)                              // bits 11..8 in regs
#define QB(e) ((((t) >> 4) << 8) | ((e) << 4) | ((t) & 15)) // bits 7..4  in regs
#define QC(e) (((t) << 4) | (e))                            // bits 3..0  in regs

#define SB() __builtin_amdgcn_sched_barrier(0)

// tab[(d*2048 + t*8 + p)*2] = {cos,sin} in the main kernel's access order.
__global__ void build_tab_kernel(const float* __restrict__ params,
                                 float* __restrict__ tab) {
    int idx = blockIdx.x * 256 + threadIdx.x;
    if (idx >= NSTEPS * HALFW) return;
    int d  = idx >> 11;
    int j  = idx & (HALFW - 1);
    int t  = j >> 3;
    int p  = j & 7;
    int dd = d % 12;
    int grp = dd >> 2;            // 0: bits 11..8, 1: bits 7..4, 2: bits 3..0
    int k  = 3 - (dd & 3);        // butterfly bit within the nibble
    int e0 = ((p >> k) << (k + 1)) | (p & ((1 << k) - 1)); // insert 0 at bit k
    int q0;
    if (grp == 0)      q0 = (e0 << 8) | t;
    else if (grp == 1) q0 = ((t >> 4) << 8) | (e0 << 4) | (t & 15);
    else               q0 = (t << 4) | e0;
    int l = ((q0 << dd) | (q0 >> (12 - dd))) & 0xFFF;       // rotl12(q0, dd)
    l &= 0x7FF;
    float theta = params[l * NSTEPS + d];   // params (2048, 24) row-major
    float s, c;
    sincosf(theta, &s, &c);
    tab[2 * idx]     = c;
    tab[2 * idx + 1] = s;
}

// SROA-safe 16-float load (4x dwordx4, scalar unpack, no local punning).
__device__ __forceinline__ void ldcs(float (&dst)[16], const float* __restrict__ p) {
    const float4* ap = (const float4*)p;
    float4 q0 = ap[0], q1 = ap[1], q2 = ap[2], q3 = ap[3];
    dst[0]  = q0.x; dst[1]  = q0.y; dst[2]  = q0.z; dst[3]  = q0.w;
    dst[4]  = q1.x; dst[5]  = q1.y; dst[6]  = q1.z; dst[7]  = q1.w;
    dst[8]  = q2.x; dst[9]  = q2.y; dst[10] = q2.z; dst[11] = q2.w;
    dst[12] = q3.x; dst[13] = q3.y; dst[14] = q3.z; dst[15] = q3.w;
}

// One butterfly step (bit KK) on rows [R0, R0+NR).
template<int KK, int R0, int NR>
__device__ __forceinline__ void butterfly_rows(float (&r)[ROWS][16],
                                               const float (&cs)[16]) {
    #pragma unroll
    for (int p = 0; p < 8; ++p) {
        const int e0 = ((p >> KK) << (KK + 1)) | (p & ((1 << KK) - 1));
        const int e1 = e0 | (1 << KK);
        const float c = cs[2 * p], s = cs[2 * p + 1];
        #pragma unroll
        for (int rr = R0; rr < R0 + NR; ++rr) {
            const float v0 = r[rr][e0], v1 = r[rr][e1];
            r[rr][e0] = fmaf(c, v0, s * v1);
            r[rr][e1] = fmaf(c, v1, -s * v0);
        }
    }
}

// 4 butterfly steps on rows [R0, R0+NR). If PF, reload each cs buffer with
// the NEXT group's corresponding step right after its last use (this must
// only be enabled on the FINAL row-pass of a group).
template<int BASE, int R0, int NR, bool PF>
__device__ __forceinline__ void group4_rows(float (&r)[ROWS][16],
        float (&c0)[16], float (&c1)[16], float (&c2)[16], float (&c3)[16],
        const float* __restrict__ tb) {
    butterfly_rows<3, R0, NR>(r, c0);
    if constexpr (PF) { ldcs(c0, tb + (BASE + 4) * 4096); SB(); }
    butterfly_rows<2, R0, NR>(r, c1);
    if constexpr (PF) { ldcs(c1, tb + (BASE + 5) * 4096); SB(); }
    butterfly_rows<1, R0, NR>(r, c2);
    if constexpr (PF) { ldcs(c2, tb + (BASE + 6) * 4096); SB(); }
    butterfly_rows<0, R0, NR>(r, c3);
    if constexpr (PF) { ldcs(c3, tb + (BASE + 7) * 4096); SB(); }
}

// Fused transition + next group, 32 KiB LDS (2 row-buffers), 4 barriers:
//   store r0/r1 ; sync ; load r0/r1 ; sync ;
//   store r2/r3 ; [compute group on rows 0/1 — covers the stores] ; sync ;
//   load  r2/r3 ; [compute group on rows 2/3 + cs prefetch] ; [tail sync]
// Rows are fully independent, so computing rows 0/1 before rows 2/3 have
// been transposed is legal. Swizzled b32 pattern per buffer is identical to
// the measured-conflict-free TRANS.
#define TG(BASE, QS, QD, PFN, TAILSYNC) do {                                  \
    _Pragma("unroll")                                                         \
    for (int e = 0; e < 16; ++e) {                                            \
        const int a = SWZ(QS(e));                                             \
        lds0[a] = r[0][e];                                                    \
        lds1[a] = r[1][e];                                                    \
    }                                                                         \
    __syncthreads();                                                          \
    _Pragma("unroll")                                                         \
    for (int e = 0; e < 16; ++e) {                                            \
        const int a = SWZ(QD(e));                                             \
        r[0][e] = lds0[a];                                                    \
        r[1][e] = lds1[a];                                                    \
    }                                                                         \
    __syncthreads();                                                          \
    _Pragma("unroll")                                                         \
    for (int e = 0; e < 16; ++e) {                                            \
        const int a = SWZ(QS(e));                                             \
        lds0[a] = r[2][e];                                                    \
        lds1[a] = r[3][e];                                                    \
    }                                                                         \
    group4_rows<BASE, 0, 2, false>(r, c0, c1, c2, c3, tb);                    \
    __syncthreads();                                                          \
    _Pragma("unroll")                                                         \
    for (int e = 0; e < 16; ++e) {                                            \
        const int a = SWZ(QD(e));                                             \
        r[2][e] = lds0[a];                                                    \
        r[3][e] = lds1[a];                                                    \
    }                                                                         \
    group4_rows<BASE, 2, 2, PFN>(r, c0, c1, c2, c3, tb);                      \
    if (TAILSYNC) __syncthreads();                                            \
} while (0)

// (256,2): NO allocator pressure — round-1's (256,4) forced VGPR 100->64 and
// spilled 1.5 GB/dispatch to scratch (FETCH 586 MB, WRITE 940 MB). Hardware
// occupancy follows ACTUAL VGPR count: at ~100 VGPR + 32 KiB LDS we get
// 4-5 blocks/CU without touching the allocator.
__global__ __launch_bounds__(256, 2)
void bfly_kernel(const float* __restrict__ X,
                 const float* __restrict__ tab,
                 float* __restrict__ Y) {
    __shared__ float lds0[4096];       // 2 x 16 KiB = 32 KiB
    __shared__ float lds1[4096];
    const int t = threadIdx.x;
    const size_t row0 = (size_t)blockIdx.x * ROWS;

    const float* tb = tab + t * 16;
    float c0[16], c1[16], c2[16], c3[16];
    ldcs(c0, tb + 0 * 4096);
    ldcs(c1, tb + 1 * 4096);
    ldcs(c2, tb + 2 * 4096);
    ldcs(c3, tb + 3 * 4096);
    SB();

    float r[ROWS][16];
    #pragma unroll
    for (int rr = 0; rr < ROWS; ++rr) {
        const float* xr = X + (row0 + rr) * 4096;
        #pragma unroll
        for (int e = 0; e < 16; ++e)
            r[rr][e] = xr[QA(e)];  // coalesced: consecutive lanes, consecutive addr
    }

    group4_rows<0, 0, 4, true>(r, c0, c1, c2, c3, tb);  // steps 0..3 (bits 11..8)
    TG(4,  QA, QB, true,  true);                        // steps 4..7   (bits 7..4)
    TG(8,  QB, QC, true,  true);                        // steps 8..11  (bits 3..0)
    TG(12, QC, QA, true,  true);                        // steps 12..15 (bits 11..8)
    TG(16, QA, QB, true,  true);                        // steps 16..19 (bits 7..4)
    TG(20, QB, QC, false, false);                       // steps 20..23 (bits 3..0)

    // grouping C: thread t holds 16 consecutive outputs -> 4x float4 stores
    #pragma unroll
    for (int rr = 0; rr < ROWS; ++rr) {
        float* yr = Y + (row0 + rr) * 4096;
        #pragma unroll
        for (int v = 0; v < 4; ++v) {
            float4 o;
            o.x = r[rr][4 * v + 0];
            o.y = r[rr][4 * v + 1];
            o.z = r[rr][4 * v + 2];
            o.w = r[rr][4 * v + 3];
            *(float4*)&yr[t * 16 + 4 * v] = o;
        }
    }
}

extern "C" void kernel_launch(void* const* d_in, const int* in_sizes, int n_in,
                              void* d_out, int out_size, void* d_ws, size_t ws_size,
                              hipStream_t stream) {
    const float* X      = (const float*)d_in[0];
    const float* params = (const float*)d_in[1];
    float* out = (float*)d_out;
    float* tab = (float*)d_ws;   // 24*2048*2*4 = 393,216 bytes

    hipLaunchKernelGGL(build_tab_kernel,
                       dim3((NSTEPS * HALFW + 255) / 256), dim3(256), 0, stream,
                       params, tab);
    hipLaunchKernelGGL(bfly_kernel,
                       dim3(8192 / ROWS), dim3(256), 0, stream,
                       X, tab, out);
}

// Round 3
// 94.037 us; speedup vs baseline: 3.7705x; 1.1499x over previous
//
#include <hip/hip_runtime.h>

#define NSTEPS 24
#define HALFW  2048
#define ROWS   2
#define INV2PI 0.15915494309189535f

// Round-1 swizzle — MEASURED 0 bank conflicts at b32 scalar.
#define SWZ(q) ((q) ^ (((q) >> 4) & 31))
#define QA(e) (((e) << 8) | t)                              // bits 11..8 in regs
#define QB(e) ((((t) >> 4) << 8) | ((e) << 4) | ((t) & 15)) // bits 7..4  in regs
#define QC(e) (((t) << 4) | (e))                            // bits 3..0  in regs

#define SB() __builtin_amdgcn_sched_barrier(0)

// tab[d*2048 + t*8 + p] = theta/(2*pi)  (REVOLUTIONS, for v_sin/v_cos).
// Same verified index mapping as rounds 0-2; only the payload changed.
__global__ void build_tab_kernel(const float* __restrict__ params,
                                 float* __restrict__ tab) {
    int idx = blockIdx.x * 256 + threadIdx.x;
    if (idx >= NSTEPS * HALFW) return;
    int d  = idx >> 11;
    int j  = idx & (HALFW - 1);
    int t  = j >> 3;
    int p  = j & 7;
    int dd = d % 12;
    int grp = dd >> 2;            // 0: bits 11..8, 1: bits 7..4, 2: bits 3..0
    int k  = 3 - (dd & 3);        // butterfly bit within the nibble
    int e0 = ((p >> k) << (k + 1)) | (p & ((1 << k) - 1)); // insert 0 at bit k
    int q0;
    if (grp == 0)      q0 = (e0 << 8) | t;
    else if (grp == 1) q0 = ((t >> 4) << 8) | (e0 << 4) | (t & 15);
    else               q0 = (t << 4) | e0;
    int l = ((q0 << dd) | (q0 >> (12 - dd))) & 0xFFF;       // rotl12(q0, dd)
    l &= 0x7FF;
    float theta = params[l * NSTEPS + d];   // params (2048, 24) row-major
    tab[idx] = theta * INV2PI;
}

// 8-float theta load (2x dwordx4, scalar unpack, SROA-safe).
__device__ __forceinline__ void ldth(float (&dst)[8], const float* __restrict__ p) {
    const float4* ap = (const float4*)p;
    float4 q0 = ap[0], q1 = ap[1];
    dst[0] = q0.x; dst[1] = q0.y; dst[2] = q0.z; dst[3] = q0.w;
    dst[4] = q1.x; dst[5] = q1.y; dst[6] = q1.z; dst[7] = q1.w;
}

// One butterfly step (bit KK), c/s recomputed from theta (revolutions) via
// hw v_cos_f32/v_sin_f32 — 2 instrs/pair, keeps only th[8] live instead of
// cs[16] per buffered step. Input range |rev|<=0.5 is in hw range.
template<int KK>
__device__ __forceinline__ void bfly(float (&r)[ROWS][16], const float (&th)[8]) {
    #pragma unroll
    for (int p = 0; p < 8; ++p) {
        const int e0 = ((p >> KK) << (KK + 1)) | (p & ((1 << KK) - 1));
        const int e1 = e0 | (1 << KK);
        const float c = __builtin_amdgcn_cosf(th[p]);
        const float s = __builtin_amdgcn_sinf(th[p]);
        #pragma unroll
        for (int rr = 0; rr < ROWS; ++rr) {
            const float v0 = r[rr][e0], v1 = r[rr][e1];
            r[rr][e0] = fmaf(c, v0, s * v1);
            r[rr][e1] = fmaf(c, v1, -s * v0);
        }
    }
}

// 4 butterfly steps; theta double-buffer (t0a=BASE, t1a=BASE+1 on entry),
// distance-2 prefetch pinned after each last use (r8/r9-proven SB pattern).
// Exit invariant: t0a=BASE+4, t1a=BASE+5 (when in range).
template<int BASE>
__device__ __forceinline__ void group4(float (&r)[ROWS][16],
        float (&t0a)[8], float (&t1a)[8], const float* __restrict__ tb) {
    bfly<3>(r, t0a);
    if constexpr (BASE + 2 < NSTEPS) { ldth(t0a, tb + (BASE + 2) * 2048); SB(); }
    bfly<2>(r, t1a);
    if constexpr (BASE + 3 < NSTEPS) { ldth(t1a, tb + (BASE + 3) * 2048); SB(); }
    bfly<1>(r, t0a);
    if constexpr (BASE + 4 < NSTEPS) { ldth(t0a, tb + (BASE + 4) * 2048); SB(); }
    bfly<0>(r, t1a);
    if constexpr (BASE + 5 < NSTEPS) { ldth(t1a, tb + (BASE + 5) * 2048); SB(); }
}

// 2-row transition, 2 barriers, same measured-conflict-free b32 pattern.
#define TRANS(QS, QD) do {                                                    \
    _Pragma("unroll")                                                         \
    for (int e = 0; e < 16; ++e) {                                            \
        const int a = SWZ(QS(e));                                             \
        lds0[a] = r[0][e];                                                    \
        lds1[a] = r[1][e];                                                    \
    }                                                                         \
    __syncthreads();                                                          \
    _Pragma("unroll")                                                         \
    for (int e = 0; e < 16; ++e) {                                            \
        const int a = SWZ(QD(e));                                             \
        r[0][e] = lds0[a];                                                    \
        r[1][e] = lds1[a];                                                    \
    }                                                                         \
    __syncthreads();                                                          \
} while (0)

// Pool model (fit to rounds 0-2): waves/SIMD = floor(256 / VGPR).
// ROWS=2 + theta-recompute targets ~70 live VGPRs -> 3 waves/SIMD.
// (256,3) caps allocator at 85 — comfortably above essential liveness
// (round-1 lesson: never force below it).
__global__ __launch_bounds__(256, 3)
void bfly_kernel(const float* __restrict__ X,
                 const float* __restrict__ tab,
                 float* __restrict__ Y) {
    __shared__ float lds0[4096];       // 2 x 16 KiB = 32 KiB
    __shared__ float lds1[4096];
    const int t = threadIdx.x;
    const size_t row0 = (size_t)blockIdx.x * ROWS;

    const float* tb = tab + t * 8;
    float t0a[8], t1a[8];
    ldth(t0a, tb + 0 * 2048);
    ldth(t1a, tb + 1 * 2048);
    SB();

    float r[ROWS][16];
    #pragma unroll
    for (int rr = 0; rr < ROWS; ++rr) {
        const float* xr = X + (row0 + rr) * 4096;
        #pragma unroll
        for (int e = 0; e < 16; ++e)
            r[rr][e] = xr[QA(e)];  // coalesced: consecutive lanes, consecutive addr
    }

    group4<0 >(r, t0a, t1a, tb);   // steps 0..3   (bits 11..8)
    TRANS(QA, QB);
    group4<4 >(r, t0a, t1a, tb);   // steps 4..7   (bits 7..4)
    TRANS(QB, QC);
    group4<8 >(r, t0a, t1a, tb);   // steps 8..11  (bits 3..0)
    TRANS(QC, QA);
    group4<12>(r, t0a, t1a, tb);   // steps 12..15 (bits 11..8)
    TRANS(QA, QB);
    group4<16>(r, t0a, t1a, tb);   // steps 16..19 (bits 7..4)
    TRANS(QB, QC);
    group4<20>(r, t0a, t1a, tb);   // steps 20..23 (bits 3..0)

    // grouping C: thread t holds 16 consecutive outputs -> 4x float4 stores
    #pragma unroll
    for (int rr = 0; rr < ROWS; ++rr) {
        float* yr = Y + (row0 + rr) * 4096;
        #pragma unroll
        for (int v = 0; v < 4; ++v) {
            float4 o;
            o.x = r[rr][4 * v + 0];
            o.y = r[rr][4 * v + 1];
            o.z = r[rr][4 * v + 2];
            o.w = r[rr][4 * v + 3];
            *(float4*)&yr[t * 16 + 4 * v] = o;
        }
    }
}

extern "C" void kernel_launch(void* const* d_in, const int* in_sizes, int n_in,
                              void* d_out, int out_size, void* d_ws, size_t ws_size,
                              hipStream_t stream) {
    const float* X      = (const float*)d_in[0];
    const float* params = (const float*)d_in[1];
    float* out = (float*)d_out;
    float* tab = (float*)d_ws;   // 24*2048*4 = 196,608 bytes (theta only)

    hipLaunchKernelGGL(build_tab_kernel,
                       dim3((NSTEPS * HALFW + 255) / 256), dim3(256), 0, stream,
                       params, tab);
    hipLaunchKernelGGL(bfly_kernel,
                       dim3(8192 / ROWS), dim3(256), 0, stream,
                       X, tab, out);
}

// Round 4
// 92.803 us; speedup vs baseline: 3.8207x; 1.0133x over previous
//
#include <hip/hip_runtime.h>

#define NSTEPS 24
#define HALFW  2048
#define ROWS   2
#define INV2PI 0.15915494309189535f

typedef float float2v __attribute__((ext_vector_type(2)));

// Round-1 swizzle — MEASURED 0 bank conflicts at b32 scalar.
#define SWZ(q) ((q) ^ (((q) >> 4) & 31))
#define QA(e) (((e) << 8) | t)                              // bits 11..8 in regs
#define QB(e) ((((t) >> 4) << 8) | ((e) << 4) | ((t) & 15)) // bits 7..4  in regs
#define QC(e) (((t) << 4) | (e))                            // bits 3..0  in regs

#define SB() __builtin_amdgcn_sched_barrier(0)

// tab[d*2048 + t*8 + p] = theta/(2*pi)  (REVOLUTIONS, for v_sin/v_cos).
// Same verified index mapping as rounds 0-3; payload is theta/2pi.
__global__ void build_tab_kernel(const float* __restrict__ params,
                                 float* __restrict__ tab) {
    int idx = blockIdx.x * 256 + threadIdx.x;
    if (idx >= NSTEPS * HALFW) return;
    int d  = idx >> 11;
    int j  = idx & (HALFW - 1);
    int t  = j >> 3;
    int p  = j & 7;
    int dd = d % 12;
    int grp = dd >> 2;            // 0: bits 11..8, 1: bits 7..4, 2: bits 3..0
    int k  = 3 - (dd & 3);        // butterfly bit within the nibble
    int e0 = ((p >> k) << (k + 1)) | (p & ((1 << k) - 1)); // insert 0 at bit k
    int q0;
    if (grp == 0)      q0 = (e0 << 8) | t;
    else if (grp == 1) q0 = ((t >> 4) << 8) | (e0 << 4) | (t & 15);
    else               q0 = (t << 4) | e0;
    int l = ((q0 << dd) | (q0 >> (12 - dd))) & 0xFFF;       // rotl12(q0, dd)
    l &= 0x7FF;
    float theta = params[l * NSTEPS + d];   // params (2048, 24) row-major
    tab[idx] = theta * INV2PI;
}

// 8-float theta load (2x dwordx4, scalar unpack, SROA-safe).
__device__ __forceinline__ void ldth(float (&dst)[8], const float* __restrict__ p) {
    const float4* ap = (const float4*)p;
    float4 q0 = ap[0], q1 = ap[1];
    dst[0] = q0.x; dst[1] = q0.y; dst[2] = q0.z; dst[3] = q0.w;
    dst[4] = q1.x; dst[5] = q1.y; dst[6] = q1.z; dst[7] = q1.w;
}

// One butterfly step (bit KK) on BOTH rows at once via packed fp32.
// rp[e] = {row0[e], row1[e]}; same (c,s) for both halves -> the rotation is
// 4x v_pk_{mul,fma}_f32 per pair instead of 8 scalar VALU ops.
// c/s recomputed from theta (revolutions) via hw v_cos/v_sin (quarter-rate
// TRANS pipe, |rev|<=0.5 in hw range).
template<int KK>
__device__ __forceinline__ void bfly(float2v (&rp)[16], const float (&th)[8]) {
    #pragma unroll
    for (int p = 0; p < 8; ++p) {
        const int e0 = ((p >> KK) << (KK + 1)) | (p & ((1 << KK) - 1));
        const int e1 = e0 | (1 << KK);
        const float c = __builtin_amdgcn_cosf(th[p]);
        const float s = __builtin_amdgcn_sinf(th[p]);
        const float2v cv = {c, c};
        const float2v sv = {s, s};
        const float2v v0 = rp[e0], v1 = rp[e1];
        rp[e0] = __builtin_elementwise_fma(cv, v0, sv * v1);
        rp[e1] = __builtin_elementwise_fma(cv, v1, -(sv * v0));
    }
}

// 4 butterfly steps; theta double-buffer (t0a=BASE, t1a=BASE+1 on entry),
// distance-2 prefetch pinned after each last use (r8/r9-proven SB pattern).
template<int BASE>
__device__ __forceinline__ void group4(float2v (&rp)[16],
        float (&t0a)[8], float (&t1a)[8], const float* __restrict__ tb) {
    bfly<3>(rp, t0a);
    if constexpr (BASE + 2 < NSTEPS) { ldth(t0a, tb + (BASE + 2) * 2048); SB(); }
    bfly<2>(rp, t1a);
    if constexpr (BASE + 3 < NSTEPS) { ldth(t1a, tb + (BASE + 3) * 2048); SB(); }
    bfly<1>(rp, t0a);
    if constexpr (BASE + 4 < NSTEPS) { ldth(t0a, tb + (BASE + 4) * 2048); SB(); }
    bfly<0>(rp, t1a);
    if constexpr (BASE + 5 < NSTEPS) { ldth(t1a, tb + (BASE + 5) * 2048); SB(); }
}

// 2-row transition, 2 barriers, same measured-conflict-free b32 pattern
// (components extracted; DS traffic identical to round 3).
#define TRANS(QS, QD) do {                                                    \
    _Pragma("unroll")                                                         \
    for (int e = 0; e < 16; ++e) {                                            \
        const int a = SWZ(QS(e));                                             \
        lds0[a] = rp[e].x;                                                    \
        lds1[a] = rp[e].y;                                                    \
    }                                                                         \
    __syncthreads();                                                          \
    _Pragma("unroll")                                                         \
    for (int e = 0; e < 16; ++e) {                                            \
        const int a = SWZ(QD(e));                                             \
        rp[e].x = lds0[a];                                                    \
        rp[e].y = lds1[a];                                                    \
    }                                                                         \
    __syncthreads();                                                          \
} while (0)

// Pool model (fit to rounds 0-3): waves/SIMD = floor(256 / VGPR).
// Packed rows keep live state identical to round 3 (~60 VGPR).
__global__ __launch_bounds__(256, 3)
void bfly_kernel(const float* __restrict__ X,
                 const float* __restrict__ tab,
                 float* __restrict__ Y) {
    __shared__ float lds0[4096];       // 2 x 16 KiB = 32 KiB
    __shared__ float lds1[4096];
    const int t = threadIdx.x;
    const size_t row0 = (size_t)blockIdx.x * ROWS;

    const float* tb = tab + t * 8;
    float t0a[8], t1a[8];
    ldth(t0a, tb + 0 * 2048);
    ldth(t1a, tb + 1 * 2048);
    SB();

    float2v rp[16];
    {
        const float* xr0 = X + (row0 + 0) * 4096;
        const float* xr1 = X + (row0 + 1) * 4096;
        #pragma unroll
        for (int e = 0; e < 16; ++e) {
            rp[e].x = xr0[QA(e)];  // coalesced: consecutive lanes, consecutive addr
            rp[e].y = xr1[QA(e)];
        }
    }

    group4<0 >(rp, t0a, t1a, tb);   // steps 0..3   (bits 11..8)
    TRANS(QA, QB);
    group4<4 >(rp, t0a, t1a, tb);   // steps 4..7   (bits 7..4)
    TRANS(QB, QC);
    group4<8 >(rp, t0a, t1a, tb);   // steps 8..11  (bits 3..0)
    TRANS(QC, QA);
    group4<12>(rp, t0a, t1a, tb);   // steps 12..15 (bits 11..8)
    TRANS(QA, QB);
    group4<16>(rp, t0a, t1a, tb);   // steps 16..19 (bits 7..4)
    TRANS(QB, QC);
    group4<20>(rp, t0a, t1a, tb);   // steps 20..23 (bits 3..0)

    // grouping C: thread t holds 16 consecutive outputs per row -> float4 stores
    {
        float* yr0 = Y + (row0 + 0) * 4096;
        float* yr1 = Y + (row0 + 1) * 4096;
        #pragma unroll
        for (int v = 0; v < 4; ++v) {
            float4 o0, o1;
            o0.x = rp[4 * v + 0].x; o1.x = rp[4 * v + 0].y;
            o0.y = rp[4 * v + 1].x; o1.y = rp[4 * v + 1].y;
            o0.z = rp[4 * v + 2].x; o1.z = rp[4 * v + 2].y;
            o0.w = rp[4 * v + 3].x; o1.w = rp[4 * v + 3].y;
            *(float4*)&yr0[t * 16 + 4 * v] = o0;
            *(float4*)&yr1[t * 16 + 4 * v] = o1;
        }
    }
}

extern "C" void kernel_launch(void* const* d_in, const int* in_sizes, int n_in,
                              void* d_out, int out_size, void* d_ws, size_t ws_size,
                              hipStream_t stream) {
    const float* X      = (const float*)d_in[0];
    const float* params = (const float*)d_in[1];
    float* out = (float*)d_out;
    float* tab = (float*)d_ws;   // 24*2048*4 = 196,608 bytes (theta only)

    hipLaunchKernelGGL(build_tab_kernel,
                       dim3((NSTEPS * HALFW + 255) / 256), dim3(256), 0, stream,
                       params, tab);
    hipLaunchKernelGGL(bfly_kernel,
                       dim3(8192 / ROWS), dim3(256), 0, stream,
                       X, tab, out);
}